// Round 1
// baseline (1328.126 us; speedup 1.0000x reference)
//
#include <hip/hip_runtime.h>
#include <hip/hip_bf16.h>

#define BB 2
#define TT 2048
#define CCH 1024
#define HH 16
#define HD 64
#define EE 8
#define FF 2048
#define NTOK (BB*TT)

typedef __bf16 bf16x8 __attribute__((ext_vector_type(8)));
typedef float f32x4 __attribute__((ext_vector_type(4)));

static __device__ __forceinline__ unsigned short f2bf(float f) {
  union { float f; unsigned u; } v; v.f = f;
  unsigned u = v.u;
  u += 0x7fffu + ((u >> 16) & 1u);
  return (unsigned short)(u >> 16);
}
static __device__ __forceinline__ float bf2f(unsigned short h) {
  union { unsigned u; float f; } v; v.u = ((unsigned)h) << 16;
  return v.f;
}

// ---------------- transpose fp32 (R x C) -> bf16 (C x R), batched over z ----
__global__ __launch_bounds__(256) void k_transpose(const float* __restrict__ in,
    unsigned short* __restrict__ out, int R, int Cc) {
  __shared__ float tile[32][33];
  size_t zoff = (size_t)blockIdx.z * (size_t)R * (size_t)Cc;
  int r0 = blockIdx.y * 32, c0 = blockIdx.x * 32;
  int tx = threadIdx.x, ty = threadIdx.y;
#pragma unroll
  for (int ii = 0; ii < 4; ++ii) {
    int i = ty + ii * 8;
    tile[i][tx] = in[zoff + (size_t)(r0 + i) * Cc + c0 + tx];
  }
  __syncthreads();
#pragma unroll
  for (int ii = 0; ii < 4; ++ii) {
    int i = ty + ii * 8;
    out[zoff + (size_t)(c0 + i) * R + r0 + tx] = f2bf(tile[tx][i]);
  }
}

// ---------------- layernorm row kernel: fp32 in -> bf16 out ----------------
__global__ __launch_bounds__(256) void k_ln(const float* __restrict__ x,
    const float* __restrict__ w, unsigned short* __restrict__ out) {
  int row = blockIdx.x;
  const float* xr = x + (size_t)row * CCH;
  int tid = threadIdx.x;
  float4 v = *(const float4*)&xr[tid * 4];
  float s = v.x + v.y + v.z + v.w;
  float ss = v.x * v.x + v.y * v.y + v.z * v.z + v.w * v.w;
#pragma unroll
  for (int off = 32; off; off >>= 1) { s += __shfl_xor(s, off); ss += __shfl_xor(ss, off); }
  __shared__ float red[8];
  int wv = tid >> 6, l = tid & 63;
  if (l == 0) { red[wv] = s; red[4 + wv] = ss; }
  __syncthreads();
  s = red[0] + red[1] + red[2] + red[3];
  ss = red[4] + red[5] + red[6] + red[7];
  float mean = s * (1.f / CCH);
  float var = ss * (1.f / CCH) - mean * mean;
  float inv = rsqrtf(var + 1e-5f);
  float4 w4 = *(const float4*)&w[tid * 4];
  ushort4 o;
  o.x = f2bf((v.x - mean) * inv * w4.x);
  o.y = f2bf((v.y - mean) * inv * w4.y);
  o.z = f2bf((v.z - mean) * inv * w4.z);
  o.w = f2bf((v.w - mean) * inv * w4.w);
  *(ushort4*)&out[(size_t)row * CCH + tid * 4] = o;
}

// ---------------- generic GEMM: C(MxN) = A(MxK,bf16) * BT(NxK,bf16)^T -------
// EPI 0: bf16 out.  EPI 1: f32 out = acc + resid.
template<int EPI>
__global__ __launch_bounds__(256) void k_gemm_bt(
    const unsigned short* __restrict__ A, const unsigned short* __restrict__ BT,
    unsigned short* __restrict__ Cb, float* __restrict__ Cf,
    const float* __restrict__ resid, int M, int N, int K)
{
  __shared__ __align__(16) unsigned short As[64][40];
  __shared__ __align__(16) unsigned short Bs[64][40];
  int m0 = blockIdx.x * 64, n0 = blockIdx.y * 64;
  int tid = threadIdx.x;
  int l = tid & 63, w = tid >> 6;
  int srow = tid >> 2, sch = (tid & 3) * 8;
  int frow = l & 15, fch = (l >> 4) * 8;
  f32x4 acc[4] = {};
  for (int k0 = 0; k0 < K; k0 += 32) {
    __syncthreads();
    *(uint4*)&As[srow][sch] = *(const uint4*)&A[(size_t)(m0 + srow) * K + k0 + sch];
    *(uint4*)&Bs[srow][sch] = *(const uint4*)&BT[(size_t)(n0 + srow) * K + k0 + sch];
    __syncthreads();
    bf16x8 af = *(const bf16x8*)&As[16 * w + frow][fch];
#pragma unroll
    for (int nb = 0; nb < 4; ++nb) {
      bf16x8 bf = *(const bf16x8*)&Bs[nb * 16 + frow][fch];
      acc[nb] = __builtin_amdgcn_mfma_f32_16x16x32_bf16(af, bf, acc[nb], 0, 0, 0);
    }
  }
  int rbase = m0 + 16 * w + 4 * (l >> 4);
  int cbase = n0 + (l & 15);
#pragma unroll
  for (int nb = 0; nb < 4; ++nb)
#pragma unroll
    for (int r = 0; r < 4; ++r) {
      int row = rbase + r, col = cbase + nb * 16;
      if (EPI == 0) Cb[(size_t)row * N + col] = f2bf(acc[nb][r]);
      else Cf[(size_t)row * N + col] = acc[nb][r] + resid[(size_t)row * N + col];
    }
}

// ---------------- flash attention (fp32 VALU, online softmax) --------------
__global__ __launch_bounds__(256) void k_attn(const unsigned short* __restrict__ qkv,
    unsigned short* __restrict__ yout)
{
  int qt = blockIdx.x, h = blockIdx.y, b = blockIdx.z;
  int tid = threadIdx.x;
  int qrow = tid >> 2, sub = tid & 3;
  int q = qt * 64 + qrow;
  const size_t rs = 3 * CCH;
  const unsigned short* qp = qkv + (size_t)(b * TT + q) * rs + h * HD + sub * 16;
  float qv[16];
#pragma unroll
  for (int j = 0; j < 16; ++j) qv[j] = bf2f(qp[j]) * 0.125f;
  __shared__ __align__(16) float Ks[32 * 68];
  __shared__ __align__(16) float Vs[32 * 68];
  float ov[16] = {};
  float m = -INFINITY, lsum = 0.f;
  int nkb = qt * 2 + 2;
  int krow = tid >> 3, kch = (tid & 7) * 8;
  for (int kb = 0; kb < nkb; ++kb) {
    int k0 = kb * 32;
    __syncthreads();
    {
      const unsigned short* kp = qkv + (size_t)(b * TT + k0 + krow) * rs + CCH + h * HD + kch;
      const unsigned short* vp = kp + CCH;
      uint4 rk = *(const uint4*)kp;
      uint4 rv = *(const uint4*)vp;
      float4 a, c;
      a.x = bf2f((unsigned short)(rk.x & 0xffff)); a.y = bf2f((unsigned short)(rk.x >> 16));
      a.z = bf2f((unsigned short)(rk.y & 0xffff)); a.w = bf2f((unsigned short)(rk.y >> 16));
      c.x = bf2f((unsigned short)(rk.z & 0xffff)); c.y = bf2f((unsigned short)(rk.z >> 16));
      c.z = bf2f((unsigned short)(rk.w & 0xffff)); c.w = bf2f((unsigned short)(rk.w >> 16));
      *(float4*)&Ks[krow * 68 + kch] = a;
      *(float4*)&Ks[krow * 68 + kch + 4] = c;
      a.x = bf2f((unsigned short)(rv.x & 0xffff)); a.y = bf2f((unsigned short)(rv.x >> 16));
      a.z = bf2f((unsigned short)(rv.y & 0xffff)); a.w = bf2f((unsigned short)(rv.y >> 16));
      c.x = bf2f((unsigned short)(rv.z & 0xffff)); c.y = bf2f((unsigned short)(rv.z >> 16));
      c.z = bf2f((unsigned short)(rv.w & 0xffff)); c.w = bf2f((unsigned short)(rv.w >> 16));
      *(float4*)&Vs[krow * 68 + kch] = a;
      *(float4*)&Vs[krow * 68 + kch + 4] = c;
    }
    __syncthreads();
    int klim = min(32, q - k0 + 1);
    for (int k = 0; k < klim; ++k) {
      const float* kr = &Ks[k * 68 + sub * 16];
      float p = 0.f;
#pragma unroll
      for (int j = 0; j < 16; ++j) p = fmaf(qv[j], kr[j], p);
      p += __shfl_xor(p, 1);
      p += __shfl_xor(p, 2);
      float pe;
      if (p > m) {
        float f = __expf(m - p);
        lsum *= f;
#pragma unroll
        for (int j = 0; j < 16; ++j) ov[j] *= f;
        m = p; pe = 1.f;
      } else {
        pe = __expf(p - m);
      }
      lsum += pe;
      const float* vr = &Vs[k * 68 + sub * 16];
#pragma unroll
      for (int j = 0; j < 16; ++j) ov[j] = fmaf(pe, vr[j], ov[j]);
    }
  }
  float invl = 1.f / lsum;
  unsigned short* yo = yout + (size_t)(b * TT + q) * CCH + h * HD + sub * 16;
#pragma unroll
  for (int j4 = 0; j4 < 4; ++j4) {
    ushort4 o;
    o.x = f2bf(ov[j4 * 4 + 0] * invl);
    o.y = f2bf(ov[j4 * 4 + 1] * invl);
    o.z = f2bf(ov[j4 * 4 + 2] * invl);
    o.w = f2bf(ov[j4 * 4 + 3] * invl);
    *(ushort4*)&yo[j4 * 4] = o;
  }
}

// ---------------- router: fp32 LN (recomputed) + logits + top2 -------------
__global__ __launch_bounds__(256) void k_router(const float* __restrict__ x2,
    const float* __restrict__ ln2w, const float* __restrict__ rw,
    int* __restrict__ sel, float* __restrict__ selw, int* __restrict__ counts)
{
  int token = blockIdx.x * 4 + (threadIdx.x >> 6);
  int l = threadIdx.x & 63;
  const float* xr = x2 + (size_t)token * CCH;
  float xv[16];
  float s = 0.f, ss = 0.f;
#pragma unroll
  for (int j = 0; j < 16; ++j) { float v = xr[l * 16 + j]; xv[j] = v; s += v; ss += v * v; }
#pragma unroll
  for (int off = 32; off; off >>= 1) { s += __shfl_xor(s, off); ss += __shfl_xor(ss, off); }
  float mean = s * (1.f / CCH);
  float inv = rsqrtf(ss * (1.f / CCH) - mean * mean + 1e-5f);
  float logit[8] = {};
#pragma unroll
  for (int j = 0; j < 16; ++j) {
    float nv = (xv[j] - mean) * inv * ln2w[l * 16 + j];
    const float* rr = &rw[(size_t)(l * 16 + j) * EE];
#pragma unroll
    for (int e = 0; e < 8; ++e) logit[e] = fmaf(nv, rr[e], logit[e]);
  }
#pragma unroll
  for (int e = 0; e < 8; ++e) {
    float v = logit[e];
#pragma unroll
    for (int off = 32; off; off >>= 1) v += __shfl_xor(v, off);
    logit[e] = v;
  }
  float m1 = logit[0]; int i1 = 0;
#pragma unroll
  for (int e = 1; e < 8; ++e) if (logit[e] > m1) { m1 = logit[e]; i1 = e; }
  float m2 = -INFINITY; int i2 = 0;
#pragma unroll
  for (int e = 0; e < 8; ++e) if (e != i1 && logit[e] > m2) { m2 = logit[e]; i2 = e; }
  if (l == 0) {
    float w1v = 1.f / (1.f + __expf(m2 - m1));
    sel[token * 2] = i1; sel[token * 2 + 1] = i2;
    selw[token * 2] = w1v; selw[token * 2 + 1] = 1.f - w1v;
    atomicAdd(&counts[i1], 1);
    atomicAdd(&counts[i2], 1);
  }
}

__global__ void k_offsets(const int* __restrict__ counts, int* __restrict__ offs,
                          int* __restrict__ cursors) {
  if (threadIdx.x == 0 && blockIdx.x == 0) {
    int acc = 0;
    for (int e = 0; e < 8; ++e) { offs[e] = acc; cursors[e] = acc; acc += counts[e]; }
  }
}

__global__ __launch_bounds__(256) void k_scatter(const int* __restrict__ sel,
    const float* __restrict__ selw, int* __restrict__ cursors,
    int* __restrict__ tokarr, int* __restrict__ slotarr, float* __restrict__ wgtarr)
{
  int t = blockIdx.x * 256 + threadIdx.x;
  if (t >= NTOK) return;
#pragma unroll
  for (int s2 = 0; s2 < 2; ++s2) {
    int e = sel[t * 2 + s2];
    int pos = atomicAdd(&cursors[e], 1);
    tokarr[pos] = t; slotarr[pos] = s2; wgtarr[pos] = selw[t * 2 + s2];
  }
}

// ---------------- grouped MoE GEMM1: h = gelu(xn[tok] @ w1e), bf16 ---------
__global__ __launch_bounds__(256) void k_moe_gemm1(
    const unsigned short* __restrict__ Xn, const unsigned short* __restrict__ W1T,
    unsigned short* __restrict__ Hb,
    const int* __restrict__ tokarr, const int* __restrict__ offs, const int* __restrict__ counts)
{
  int e = blockIdx.z;
  int cnt = counts[e];
  int m0 = blockIdx.x * 64;
  if (m0 >= cnt) return;
  int off = offs[e];
  int n0 = blockIdx.y * 64;
  __shared__ __align__(16) unsigned short As[64][40];
  __shared__ __align__(16) unsigned short Bs[64][40];
  int tid = threadIdx.x, l = tid & 63, w = tid >> 6;
  int srow = tid >> 2, sch = (tid & 3) * 8;
  int frow = l & 15, fch = (l >> 4) * 8;
  int atok = tokarr[off + min(m0 + srow, cnt - 1)];
  f32x4 acc[4] = {};
  for (int k0 = 0; k0 < CCH; k0 += 32) {
    __syncthreads();
    *(uint4*)&As[srow][sch] = *(const uint4*)&Xn[(size_t)atok * CCH + k0 + sch];
    *(uint4*)&Bs[srow][sch] = *(const uint4*)&W1T[(size_t)(e * FF + n0 + srow) * CCH + k0 + sch];
    __syncthreads();
    bf16x8 af = *(const bf16x8*)&As[16 * w + frow][fch];
#pragma unroll
    for (int nb = 0; nb < 4; ++nb) {
      bf16x8 bf = *(const bf16x8*)&Bs[nb * 16 + frow][fch];
      acc[nb] = __builtin_amdgcn_mfma_f32_16x16x32_bf16(af, bf, acc[nb], 0, 0, 0);
    }
  }
  int rl = 16 * w + 4 * (l >> 4);
#pragma unroll
  for (int nb = 0; nb < 4; ++nb)
#pragma unroll
    for (int r = 0; r < 4; ++r) {
      int row = m0 + rl + r;
      if (row < cnt) {
        float v = acc[nb][r];
        float g = 0.5f * v * (1.f + erff(v * 0.70710678118654752f));
        Hb[(size_t)(off + row) * FF + n0 + nb * 16 + (l & 15)] = f2bf(g);
      }
    }
}

// ---------------- grouped MoE GEMM2: yp[tok][slot] = wgt * (h @ w2e) -------
__global__ __launch_bounds__(256) void k_moe_gemm2(
    const unsigned short* __restrict__ Hb, const unsigned short* __restrict__ W2T,
    float* __restrict__ yp,
    const int* __restrict__ tokarr, const int* __restrict__ slotarr,
    const float* __restrict__ wgtarr,
    const int* __restrict__ offs, const int* __restrict__ counts)
{
  int e = blockIdx.z;
  int cnt = counts[e];
  int m0 = blockIdx.x * 64;
  if (m0 >= cnt) return;
  int off = offs[e];
  int n0 = blockIdx.y * 64;
  __shared__ __align__(16) unsigned short As[64][40];
  __shared__ __align__(16) unsigned short Bs[64][40];
  int tid = threadIdx.x, l = tid & 63, w = tid >> 6;
  int srow = tid >> 2, sch = (tid & 3) * 8;
  int frow = l & 15, fch = (l >> 4) * 8;
  size_t arow = (size_t)(off + min(m0 + srow, cnt - 1));
  f32x4 acc[4] = {};
  for (int k0 = 0; k0 < FF; k0 += 32) {
    __syncthreads();
    *(uint4*)&As[srow][sch] = *(const uint4*)&Hb[arow * FF + k0 + sch];
    *(uint4*)&Bs[srow][sch] = *(const uint4*)&W2T[(size_t)(e * CCH + n0 + srow) * FF + k0 + sch];
    __syncthreads();
    bf16x8 af = *(const bf16x8*)&As[16 * w + frow][fch];
#pragma unroll
    for (int nb = 0; nb < 4; ++nb) {
      bf16x8 bf = *(const bf16x8*)&Bs[nb * 16 + frow][fch];
      acc[nb] = __builtin_amdgcn_mfma_f32_16x16x32_bf16(af, bf, acc[nb], 0, 0, 0);
    }
  }
  int rl = 16 * w + 4 * (l >> 4);
#pragma unroll
  for (int nb = 0; nb < 4; ++nb)
#pragma unroll
    for (int r = 0; r < 4; ++r) {
      int row = m0 + rl + r;
      if (row < cnt) {
        int fl = off + row;
        int tok = tokarr[fl];
        int slot = slotarr[fl];
        float wg = wgtarr[fl];
        yp[((size_t)tok * 2 + slot) * CCH + n0 + nb * 16 + (l & 15)] = wg * acc[nb][r];
      }
    }
}

// ---------------- final combine: out = x2 + yp[:,0,:] + yp[:,1,:] ----------
__global__ __launch_bounds__(256) void k_combine(const float* __restrict__ x2,
    const float* __restrict__ yp, float* __restrict__ out)
{
  int i = blockIdx.x * 256 + threadIdx.x;  // float4 index over NTOK*256
  int n = i >> 8, cw = i & 255;
  float4 a = ((const float4*)x2)[i];
  float4 y0 = ((const float4*)yp)[(size_t)(n * 2) * 256 + cw];
  float4 y1 = ((const float4*)yp)[(size_t)(n * 2 + 1) * 256 + cw];
  float4 o;
  o.x = a.x + y0.x + y1.x;
  o.y = a.y + y0.y + y1.y;
  o.z = a.z + y0.z + y1.z;
  o.w = a.w + y0.w + y1.w;
  ((float4*)out)[i] = o;
}

extern "C" void kernel_launch(void* const* d_in, const int* in_sizes, int n_in,
                              void* d_out, int out_size, void* d_ws, size_t ws_size,
                              hipStream_t stream) {
  const float* x     = (const float*)d_in[0];
  const float* ln1w  = (const float*)d_in[1];
  const float* attnw = (const float*)d_in[2];
  const float* projw = (const float*)d_in[3];
  const float* ln2w  = (const float*)d_in[4];
  const float* routw = (const float*)d_in[5];
  const float* w1    = (const float*)d_in[6];
  const float* w2    = (const float*)d_in[7];
  char* ws = (char*)d_ws;

  unsigned short* attn_wT = (unsigned short*)(ws + 0);          //  6,291,456
  unsigned short* proj_wT = (unsigned short*)(ws + 6291456);    //  2,097,152
  unsigned short* w1T     = (unsigned short*)(ws + 8388608);    // 33,554,432
  unsigned short* w2T     = (unsigned short*)(ws + 41943040);   // 33,554,432
  unsigned short* xn      = (unsigned short*)(ws + 75497472);   //  8,388,608
  unsigned short* qkv     = (unsigned short*)(ws + 83886080);   // 25,165,824
  unsigned short* yattn   = (unsigned short*)(ws + 109051904);  //  8,388,608
  unsigned short* hbuf    = (unsigned short*)(ws + 83886080);   // alias qkv+yattn (both dead by then)
  float* x2 = (float*)(ws + 117440512);                         // 16,777,216
  float* yp = (float*)(ws + 134217728);                         // 33,554,432
  char* rbase = ws + 167772160;
  int* counts   = (int*)(rbase);
  int* cursors  = (int*)(rbase + 32);
  int* offs     = (int*)(rbase + 64);
  int* sel      = (int*)(rbase + 128);
  float* selw   = (float*)(rbase + 128 + 32768);
  int* tokarr   = (int*)(rbase + 128 + 65536);
  int* slotarr  = (int*)(rbase + 128 + 98304);
  float* wgtarr = (float*)(rbase + 128 + 131072);
  float* outp = (float*)d_out;

  hipMemsetAsync(rbase, 0, 128, stream);

  dim3 tb(32, 8);
  k_transpose<<<dim3(96, 32, 1), tb, 0, stream>>>(attnw, attn_wT, 1024, 3072);
  k_transpose<<<dim3(32, 32, 1), tb, 0, stream>>>(projw, proj_wT, 1024, 1024);
  k_transpose<<<dim3(512, 32, 1), tb, 0, stream>>>(w1, w1T, 1024, 16384);
  k_transpose<<<dim3(32, 64, 8), tb, 0, stream>>>(w2, w2T, 2048, 1024);

  k_ln<<<NTOK, 256, 0, stream>>>(x, ln1w, xn);
  k_gemm_bt<0><<<dim3(64, 48), 256, 0, stream>>>(xn, attn_wT, qkv, nullptr, nullptr,
                                                 NTOK, 3 * CCH, CCH);
  k_attn<<<dim3(32, 16, 2), 256, 0, stream>>>(qkv, yattn);
  k_gemm_bt<1><<<dim3(64, 16), 256, 0, stream>>>(yattn, proj_wT, nullptr, x2, x,
                                                 NTOK, CCH, CCH);
  k_ln<<<NTOK, 256, 0, stream>>>(x2, ln2w, xn);
  k_router<<<NTOK / 4, 256, 0, stream>>>(x2, ln2w, routw, sel, selw, counts);
  k_offsets<<<1, 64, 0, stream>>>(counts, offs, cursors);
  k_scatter<<<NTOK / 256, 256, 0, stream>>>(sel, selw, cursors, tokarr, slotarr, wgtarr);
  k_moe_gemm1<<<dim3(64, 32, 8), 256, 0, stream>>>(xn, w1T, hbuf, tokarr, offs, counts);
  k_moe_gemm2<<<dim3(64, 16, 8), 256, 0, stream>>>(hbuf, w2T, yp, tokarr, slotarr, wgtarr,
                                                   offs, counts);
  k_combine<<<4096, 256, 0, stream>>>(x2, yp, outp);
}

// Round 2
// 711.884 us; speedup vs baseline: 1.8657x; 1.8657x over previous
//
#include <hip/hip_runtime.h>
#include <hip/hip_bf16.h>

#define BB 2
#define TT 2048
#define CCH 1024
#define HH 16
#define HD 64
#define EE 8
#define FF 2048
#define NTOK (BB*TT)

typedef __bf16 bf16x8 __attribute__((ext_vector_type(8)));
typedef float f32x4 __attribute__((ext_vector_type(4)));

static __device__ __forceinline__ unsigned short f2bf(float f) {
  union { float f; unsigned u; } v; v.f = f;
  unsigned u = v.u;
  u += 0x7fffu + ((u >> 16) & 1u);
  return (unsigned short)(u >> 16);
}
static __device__ __forceinline__ float bf2f(unsigned short h) {
  union { unsigned u; float f; } v; v.u = ((unsigned)h) << 16;
  return v.f;
}

// ---------------- transpose fp32 (R x C) -> bf16 (C x R), batched over z ----
__global__ __launch_bounds__(256) void k_transpose(const float* __restrict__ in,
    unsigned short* __restrict__ out, int R, int Cc) {
  __shared__ float tile[32][33];
  size_t zoff = (size_t)blockIdx.z * (size_t)R * (size_t)Cc;
  int r0 = blockIdx.y * 32, c0 = blockIdx.x * 32;
  int tx = threadIdx.x, ty = threadIdx.y;
#pragma unroll
  for (int ii = 0; ii < 4; ++ii) {
    int i = ty + ii * 8;
    tile[i][tx] = in[zoff + (size_t)(r0 + i) * Cc + c0 + tx];
  }
  __syncthreads();
#pragma unroll
  for (int ii = 0; ii < 4; ++ii) {
    int i = ty + ii * 8;
    out[zoff + (size_t)(c0 + i) * R + r0 + tx] = f2bf(tile[tx][i]);
  }
}

// ---------------- layernorm row kernel: fp32 in -> bf16 out ----------------
__global__ __launch_bounds__(256) void k_ln(const float* __restrict__ x,
    const float* __restrict__ w, unsigned short* __restrict__ out) {
  int row = blockIdx.x;
  const float* xr = x + (size_t)row * CCH;
  int tid = threadIdx.x;
  float4 v = *(const float4*)&xr[tid * 4];
  float s = v.x + v.y + v.z + v.w;
  float ss = v.x * v.x + v.y * v.y + v.z * v.z + v.w * v.w;
#pragma unroll
  for (int off = 32; off; off >>= 1) { s += __shfl_xor(s, off); ss += __shfl_xor(ss, off); }
  __shared__ float red[8];
  int wv = tid >> 6, l = tid & 63;
  if (l == 0) { red[wv] = s; red[4 + wv] = ss; }
  __syncthreads();
  s = red[0] + red[1] + red[2] + red[3];
  ss = red[4] + red[5] + red[6] + red[7];
  float mean = s * (1.f / CCH);
  float var = ss * (1.f / CCH) - mean * mean;
  float inv = rsqrtf(var + 1e-5f);
  float4 w4 = *(const float4*)&w[tid * 4];
  ushort4 o;
  o.x = f2bf((v.x - mean) * inv * w4.x);
  o.y = f2bf((v.y - mean) * inv * w4.y);
  o.z = f2bf((v.z - mean) * inv * w4.z);
  o.w = f2bf((v.w - mean) * inv * w4.w);
  *(ushort4*)&out[(size_t)row * CCH + tid * 4] = o;
}

// ---------------- generic GEMM: C(MxN) = A(MxK,bf16) * BT(NxK,bf16)^T -------
// EPI 0: bf16 out.  EPI 1: f32 out = acc + resid.
template<int EPI>
__global__ __launch_bounds__(256) void k_gemm_bt(
    const unsigned short* __restrict__ A, const unsigned short* __restrict__ BT,
    unsigned short* __restrict__ Cb, float* __restrict__ Cf,
    const float* __restrict__ resid, int M, int N, int K)
{
  __shared__ __align__(16) unsigned short As[64][40];
  __shared__ __align__(16) unsigned short Bs[64][40];
  int m0 = blockIdx.x * 64, n0 = blockIdx.y * 64;
  int tid = threadIdx.x;
  int l = tid & 63, w = tid >> 6;
  int srow = tid >> 2, sch = (tid & 3) * 8;
  int frow = l & 15, fch = (l >> 4) * 8;
  f32x4 acc[4] = {};
  for (int k0 = 0; k0 < K; k0 += 32) {
    __syncthreads();
    *(uint4*)&As[srow][sch] = *(const uint4*)&A[(size_t)(m0 + srow) * K + k0 + sch];
    *(uint4*)&Bs[srow][sch] = *(const uint4*)&BT[(size_t)(n0 + srow) * K + k0 + sch];
    __syncthreads();
    bf16x8 af = *(const bf16x8*)&As[16 * w + frow][fch];
#pragma unroll
    for (int nb = 0; nb < 4; ++nb) {
      bf16x8 bf = *(const bf16x8*)&Bs[nb * 16 + frow][fch];
      acc[nb] = __builtin_amdgcn_mfma_f32_16x16x32_bf16(af, bf, acc[nb], 0, 0, 0);
    }
  }
  int rbase = m0 + 16 * w + 4 * (l >> 4);
  int cbase = n0 + (l & 15);
#pragma unroll
  for (int nb = 0; nb < 4; ++nb)
#pragma unroll
    for (int r = 0; r < 4; ++r) {
      int row = rbase + r, col = cbase + nb * 16;
      if (EPI == 0) Cb[(size_t)row * N + col] = f2bf(acc[nb][r]);
      else Cf[(size_t)row * N + col] = acc[nb][r] + resid[(size_t)row * N + col];
    }
}

// ---------------- MFMA flash attention ------------------------------------
// Block = 4 waves = 64 q-rows per tile; processes TWO complementary q-tiles
// (qt and 31-qt) for constant 34 KV-iterations per block (load balance).
// Wave w owns q-rows [tile*64 + w*16, +16). K staged row-major (direct MFMA
// B-operand), V staged transposed, P round-trips through per-wave LDS.
__global__ __launch_bounds__(256) void k_attn_mfma(const unsigned short* __restrict__ qkv,
    unsigned short* __restrict__ yout)
{
  int bx = blockIdx.x, h = blockIdx.y, b = blockIdx.z;
  int tid = threadIdx.x, l = tid & 63, w = tid >> 6;
  const size_t rs = 3 * CCH;
  const int NTILE = TT / 64;  // 32

  __shared__ __align__(16) unsigned short Ks[64][72];
  __shared__ __align__(16) unsigned short Vt[64][72];
  __shared__ __align__(16) unsigned short Ps[4][16][72];

  int frow = l & 15, fk = (l >> 4) * 8;   // fragment row / k-chunk
  int g4 = l >> 4;                         // row-group for C layout
  int kr = tid >> 2, kc0 = (tid & 3) * 8;  // K staging: row, col chunk (+0,+32)
  int vr = tid >> 2, vc0 = (tid & 3) * 16; // V staging: row, 16-col chunk

  for (int half = 0; half < 2; ++half) {
    int qt = half ? (NTILE - 1 - bx) : bx;
    int q0 = qt * 64;

    const unsigned short* qp = qkv + (size_t)((size_t)b * TT + q0 + w * 16 + frow) * rs + h * HD;
    bf16x8 qf0 = *(const bf16x8*)&qp[fk];
    bf16x8 qf1 = *(const bf16x8*)&qp[32 + fk];

    f32x4 oacc[4] = {};
    float mrow[4] = {-INFINITY, -INFINITY, -INFINITY, -INFINITY};
    float lrow[4] = {};

    for (int kb = 0; kb <= qt; ++kb) {
      int k0 = kb * 64;
      __syncthreads();
      // stage K row-major
      const unsigned short* kp = qkv + (size_t)((size_t)b * TT + k0 + kr) * rs + CCH + h * HD;
      *(uint4*)&Ks[kr][kc0]      = *(const uint4*)&kp[kc0];
      *(uint4*)&Ks[kr][kc0 + 32] = *(const uint4*)&kp[kc0 + 32];
      // stage V transposed
      const unsigned short* vp = qkv + (size_t)((size_t)b * TT + k0 + vr) * rs + 2 * CCH + h * HD + vc0;
      uint4 v0 = *(const uint4*)&vp[0];
      uint4 v1 = *(const uint4*)&vp[8];
      unsigned short tmp[16];
      *(uint4*)&tmp[0] = v0; *(uint4*)&tmp[8] = v1;
#pragma unroll
      for (int j = 0; j < 16; ++j) Vt[vc0 + j][vr] = tmp[j];
      __syncthreads();

      // S = Q @ K^T  (16 x 64 per wave)
      f32x4 sacc[4] = {};
#pragma unroll
      for (int nb = 0; nb < 4; ++nb) {
        bf16x8 kf0 = *(const bf16x8*)&Ks[nb * 16 + frow][fk];
        bf16x8 kf1 = *(const bf16x8*)&Ks[nb * 16 + frow][32 + fk];
        sacc[nb] = __builtin_amdgcn_mfma_f32_16x16x32_bf16(qf0, kf0, sacc[nb], 0, 0, 0);
        sacc[nb] = __builtin_amdgcn_mfma_f32_16x16x32_bf16(qf1, kf1, sacc[nb], 0, 0, 0);
      }

      // online softmax (C layout: row = 4*g4 + r, col = nb*16 + frow)
      bool diag = (kb == qt);
      float sv[4][4];
#pragma unroll
      for (int nb = 0; nb < 4; ++nb)
#pragma unroll
        for (int r = 0; r < 4; ++r) {
          float v = sacc[nb][r] * 0.125f;
          if (diag) {
            int ckv = nb * 16 + frow;
            int rq = w * 16 + 4 * g4 + r;
            if (ckv > rq) v = -INFINITY;
          }
          sv[nb][r] = v;
        }
      float fscale[4];
#pragma unroll
      for (int r = 0; r < 4; ++r) {
        float vm = fmaxf(fmaxf(sv[0][r], sv[1][r]), fmaxf(sv[2][r], sv[3][r]));
        vm = fmaxf(vm, __shfl_xor(vm, 1));
        vm = fmaxf(vm, __shfl_xor(vm, 2));
        vm = fmaxf(vm, __shfl_xor(vm, 4));
        vm = fmaxf(vm, __shfl_xor(vm, 8));
        float mnew = fmaxf(mrow[r], vm);
        float f = __expf(mrow[r] - mnew);
        mrow[r] = mnew;
        fscale[r] = f;
        float psum = 0.f;
#pragma unroll
        for (int nb = 0; nb < 4; ++nb) {
          float p = __expf(sv[nb][r] - mnew);
          sv[nb][r] = p;
          psum += p;
        }
        psum += __shfl_xor(psum, 1);
        psum += __shfl_xor(psum, 2);
        psum += __shfl_xor(psum, 4);
        psum += __shfl_xor(psum, 8);
        lrow[r] = lrow[r] * f + psum;
      }
      // rescale O, write P (bf16) to per-wave LDS
#pragma unroll
      for (int nb = 0; nb < 4; ++nb)
#pragma unroll
        for (int r = 0; r < 4; ++r) {
          oacc[nb][r] *= fscale[r];
          Ps[w][4 * g4 + r][nb * 16 + frow] = f2bf(sv[nb][r]);
        }
      // O += P @ V  (A = P rows, B^T = Vt rows)
#pragma unroll
      for (int ks = 0; ks < 2; ++ks) {
        bf16x8 pa = *(const bf16x8*)&Ps[w][frow][ks * 32 + fk];
#pragma unroll
        for (int nb = 0; nb < 4; ++nb) {
          bf16x8 vb = *(const bf16x8*)&Vt[nb * 16 + frow][ks * 32 + fk];
          oacc[nb] = __builtin_amdgcn_mfma_f32_16x16x32_bf16(pa, vb, oacc[nb], 0, 0, 0);
        }
      }
    }

    // epilogue
    unsigned short* yo = yout + (size_t)((size_t)b * TT + q0 + w * 16) * CCH + h * HD;
#pragma unroll
    for (int r = 0; r < 4; ++r) {
      float inv = 1.f / lrow[r];
      int row = 4 * g4 + r;
#pragma unroll
      for (int nb = 0; nb < 4; ++nb)
        yo[(size_t)row * CCH + nb * 16 + frow] = f2bf(oacc[nb][r] * inv);
    }
  }
}

// ---------------- router: fp32 LN (recomputed) + logits + top2 -------------
__global__ __launch_bounds__(256) void k_router(const float* __restrict__ x2,
    const float* __restrict__ ln2w, const float* __restrict__ rw,
    int* __restrict__ sel, float* __restrict__ selw, int* __restrict__ counts)
{
  int token = blockIdx.x * 4 + (threadIdx.x >> 6);
  int l = threadIdx.x & 63;
  const float* xr = x2 + (size_t)token * CCH;
  float xv[16];
  float s = 0.f, ss = 0.f;
#pragma unroll
  for (int j = 0; j < 16; ++j) { float v = xr[l * 16 + j]; xv[j] = v; s += v; ss += v * v; }
#pragma unroll
  for (int off = 32; off; off >>= 1) { s += __shfl_xor(s, off); ss += __shfl_xor(ss, off); }
  float mean = s * (1.f / CCH);
  float inv = rsqrtf(ss * (1.f / CCH) - mean * mean + 1e-5f);
  float logit[8] = {};
#pragma unroll
  for (int j = 0; j < 16; ++j) {
    float nv = (xv[j] - mean) * inv * ln2w[l * 16 + j];
    const float* rr = &rw[(size_t)(l * 16 + j) * EE];
#pragma unroll
    for (int e = 0; e < 8; ++e) logit[e] = fmaf(nv, rr[e], logit[e]);
  }
#pragma unroll
  for (int e = 0; e < 8; ++e) {
    float v = logit[e];
#pragma unroll
    for (int off = 32; off; off >>= 1) v += __shfl_xor(v, off);
    logit[e] = v;
  }
  float m1 = logit[0]; int i1 = 0;
#pragma unroll
  for (int e = 1; e < 8; ++e) if (logit[e] > m1) { m1 = logit[e]; i1 = e; }
  float m2 = -INFINITY; int i2 = 0;
#pragma unroll
  for (int e = 0; e < 8; ++e) if (e != i1 && logit[e] > m2) { m2 = logit[e]; i2 = e; }
  if (l == 0) {
    float w1v = 1.f / (1.f + __expf(m2 - m1));
    sel[token * 2] = i1; sel[token * 2 + 1] = i2;
    selw[token * 2] = w1v; selw[token * 2 + 1] = 1.f - w1v;
    atomicAdd(&counts[i1], 1);
    atomicAdd(&counts[i2], 1);
  }
}

__global__ void k_offsets(const int* __restrict__ counts, int* __restrict__ offs,
                          int* __restrict__ cursors) {
  if (threadIdx.x == 0 && blockIdx.x == 0) {
    int acc = 0;
    for (int e = 0; e < 8; ++e) { offs[e] = acc; cursors[e] = acc; acc += counts[e]; }
  }
}

__global__ __launch_bounds__(256) void k_scatter(const int* __restrict__ sel,
    const float* __restrict__ selw, int* __restrict__ cursors,
    int* __restrict__ tokarr, int* __restrict__ slotarr, float* __restrict__ wgtarr)
{
  int t = blockIdx.x * 256 + threadIdx.x;
  if (t >= NTOK) return;
#pragma unroll
  for (int s2 = 0; s2 < 2; ++s2) {
    int e = sel[t * 2 + s2];
    int pos = atomicAdd(&cursors[e], 1);
    tokarr[pos] = t; slotarr[pos] = s2; wgtarr[pos] = selw[t * 2 + s2];
  }
}

// ---------------- grouped MoE GEMM1: h = gelu(xn[tok] @ w1e), bf16 ---------
__global__ __launch_bounds__(256) void k_moe_gemm1(
    const unsigned short* __restrict__ Xn, const unsigned short* __restrict__ W1T,
    unsigned short* __restrict__ Hb,
    const int* __restrict__ tokarr, const int* __restrict__ offs, const int* __restrict__ counts)
{
  int e = blockIdx.z;
  int cnt = counts[e];
  int m0 = blockIdx.x * 64;
  if (m0 >= cnt) return;
  int off = offs[e];
  int n0 = blockIdx.y * 64;
  __shared__ __align__(16) unsigned short As[64][40];
  __shared__ __align__(16) unsigned short Bs[64][40];
  int tid = threadIdx.x, l = tid & 63, w = tid >> 6;
  int srow = tid >> 2, sch = (tid & 3) * 8;
  int frow = l & 15, fch = (l >> 4) * 8;
  int atok = tokarr[off + min(m0 + srow, cnt - 1)];
  f32x4 acc[4] = {};
  for (int k0 = 0; k0 < CCH; k0 += 32) {
    __syncthreads();
    *(uint4*)&As[srow][sch] = *(const uint4*)&Xn[(size_t)atok * CCH + k0 + sch];
    *(uint4*)&Bs[srow][sch] = *(const uint4*)&W1T[(size_t)(e * FF + n0 + srow) * CCH + k0 + sch];
    __syncthreads();
    bf16x8 af = *(const bf16x8*)&As[16 * w + frow][fch];
#pragma unroll
    for (int nb = 0; nb < 4; ++nb) {
      bf16x8 bf = *(const bf16x8*)&Bs[nb * 16 + frow][fch];
      acc[nb] = __builtin_amdgcn_mfma_f32_16x16x32_bf16(af, bf, acc[nb], 0, 0, 0);
    }
  }
  int rl = 16 * w + 4 * (l >> 4);
#pragma unroll
  for (int nb = 0; nb < 4; ++nb)
#pragma unroll
    for (int r = 0; r < 4; ++r) {
      int row = m0 + rl + r;
      if (row < cnt) {
        float v = acc[nb][r];
        float g = 0.5f * v * (1.f + erff(v * 0.70710678118654752f));
        Hb[(size_t)(off + row) * FF + n0 + nb * 16 + (l & 15)] = f2bf(g);
      }
    }
}

// ---------------- grouped MoE GEMM2: yp[tok][slot] = wgt * (h @ w2e) -------
__global__ __launch_bounds__(256) void k_moe_gemm2(
    const unsigned short* __restrict__ Hb, const unsigned short* __restrict__ W2T,
    float* __restrict__ yp,
    const int* __restrict__ tokarr, const int* __restrict__ slotarr,
    const float* __restrict__ wgtarr,
    const int* __restrict__ offs, const int* __restrict__ counts)
{
  int e = blockIdx.z;
  int cnt = counts[e];
  int m0 = blockIdx.x * 64;
  if (m0 >= cnt) return;
  int off = offs[e];
  int n0 = blockIdx.y * 64;
  __shared__ __align__(16) unsigned short As[64][40];
  __shared__ __align__(16) unsigned short Bs[64][40];
  int tid = threadIdx.x, l = tid & 63, w = tid >> 6;
  int srow = tid >> 2, sch = (tid & 3) * 8;
  int frow = l & 15, fch = (l >> 4) * 8;
  size_t arow = (size_t)(off + min(m0 + srow, cnt - 1));
  f32x4 acc[4] = {};
  for (int k0 = 0; k0 < FF; k0 += 32) {
    __syncthreads();
    *(uint4*)&As[srow][sch] = *(const uint4*)&Hb[arow * FF + k0 + sch];
    *(uint4*)&Bs[srow][sch] = *(const uint4*)&W2T[(size_t)(e * CCH + n0 + srow) * FF + k0 + sch];
    __syncthreads();
    bf16x8 af = *(const bf16x8*)&As[16 * w + frow][fch];
#pragma unroll
    for (int nb = 0; nb < 4; ++nb) {
      bf16x8 bf = *(const bf16x8*)&Bs[nb * 16 + frow][fch];
      acc[nb] = __builtin_amdgcn_mfma_f32_16x16x32_bf16(af, bf, acc[nb], 0, 0, 0);
    }
  }
  int rl = 16 * w + 4 * (l >> 4);
#pragma unroll
  for (int nb = 0; nb < 4; ++nb)
#pragma unroll
    for (int r = 0; r < 4; ++r) {
      int row = m0 + rl + r;
      if (row < cnt) {
        int fl = off + row;
        int tok = tokarr[fl];
        int slot = slotarr[fl];
        float wg = wgtarr[fl];
        yp[((size_t)tok * 2 + slot) * CCH + n0 + nb * 16 + (l & 15)] = wg * acc[nb][r];
      }
    }
}

// ---------------- final combine: out = x2 + yp[:,0,:] + yp[:,1,:] ----------
__global__ __launch_bounds__(256) void k_combine(const float* __restrict__ x2,
    const float* __restrict__ yp, float* __restrict__ out)
{
  int i = blockIdx.x * 256 + threadIdx.x;  // float4 index over NTOK*256
  int n = i >> 8, cw = i & 255;
  float4 a = ((const float4*)x2)[i];
  float4 y0 = ((const float4*)yp)[(size_t)(n * 2) * 256 + cw];
  float4 y1 = ((const float4*)yp)[(size_t)(n * 2 + 1) * 256 + cw];
  float4 o;
  o.x = a.x + y0.x + y1.x;
  o.y = a.y + y0.y + y1.y;
  o.z = a.z + y0.z + y1.z;
  o.w = a.w + y0.w + y1.w;
  ((float4*)out)[i] = o;
}

extern "C" void kernel_launch(void* const* d_in, const int* in_sizes, int n_in,
                              void* d_out, int out_size, void* d_ws, size_t ws_size,
                              hipStream_t stream) {
  const float* x     = (const float*)d_in[0];
  const float* ln1w  = (const float*)d_in[1];
  const float* attnw = (const float*)d_in[2];
  const float* projw = (const float*)d_in[3];
  const float* ln2w  = (const float*)d_in[4];
  const float* routw = (const float*)d_in[5];
  const float* w1    = (const float*)d_in[6];
  const float* w2    = (const float*)d_in[7];
  char* ws = (char*)d_ws;

  unsigned short* attn_wT = (unsigned short*)(ws + 0);          //  6,291,456
  unsigned short* proj_wT = (unsigned short*)(ws + 6291456);    //  2,097,152
  unsigned short* w1T     = (unsigned short*)(ws + 8388608);    // 33,554,432
  unsigned short* w2T     = (unsigned short*)(ws + 41943040);   // 33,554,432
  unsigned short* xn      = (unsigned short*)(ws + 75497472);   //  8,388,608
  unsigned short* qkv     = (unsigned short*)(ws + 83886080);   // 25,165,824
  unsigned short* yattn   = (unsigned short*)(ws + 109051904);  //  8,388,608
  unsigned short* hbuf    = (unsigned short*)(ws + 83886080);   // alias qkv+yattn (both dead by then)
  float* x2 = (float*)(ws + 117440512);                         // 16,777,216
  float* yp = (float*)(ws + 134217728);                         // 33,554,432
  char* rbase = ws + 167772160;
  int* counts   = (int*)(rbase);
  int* cursors  = (int*)(rbase + 32);
  int* offs     = (int*)(rbase + 64);
  int* sel      = (int*)(rbase + 128);
  float* selw   = (float*)(rbase + 128 + 32768);
  int* tokarr   = (int*)(rbase + 128 + 65536);
  int* slotarr  = (int*)(rbase + 128 + 98304);
  float* wgtarr = (float*)(rbase + 128 + 131072);
  float* outp = (float*)d_out;

  hipMemsetAsync(rbase, 0, 128, stream);

  dim3 tb(32, 8);
  k_transpose<<<dim3(96, 32, 1), tb, 0, stream>>>(attnw, attn_wT, 1024, 3072);
  k_transpose<<<dim3(32, 32, 1), tb, 0, stream>>>(projw, proj_wT, 1024, 1024);
  k_transpose<<<dim3(512, 32, 1), tb, 0, stream>>>(w1, w1T, 1024, 16384);
  k_transpose<<<dim3(32, 64, 8), tb, 0, stream>>>(w2, w2T, 2048, 1024);

  k_ln<<<NTOK, 256, 0, stream>>>(x, ln1w, xn);
  k_gemm_bt<0><<<dim3(64, 48), 256, 0, stream>>>(xn, attn_wT, qkv, nullptr, nullptr,
                                                 NTOK, 3 * CCH, CCH);
  k_attn_mfma<<<dim3(16, 16, 2), 256, 0, stream>>>(qkv, yattn);
  k_gemm_bt<1><<<dim3(64, 16), 256, 0, stream>>>(yattn, proj_wT, nullptr, x2, x,
                                                 NTOK, CCH, CCH);
  k_ln<<<NTOK, 256, 0, stream>>>(x2, ln2w, xn);
  k_router<<<NTOK / 4, 256, 0, stream>>>(x2, ln2w, routw, sel, selw, counts);
  k_offsets<<<1, 64, 0, stream>>>(counts, offs, cursors);
  k_scatter<<<NTOK / 256, 256, 0, stream>>>(sel, selw, cursors, tokarr, slotarr, wgtarr);
  k_moe_gemm1<<<dim3(64, 32, 8), 256, 0, stream>>>(xn, w1T, hbuf, tokarr, offs, counts);
  k_moe_gemm2<<<dim3(64, 16, 8), 256, 0, stream>>>(hbuf, w2T, yp, tokarr, slotarr, wgtarr,
                                                   offs, counts);
  k_combine<<<4096, 256, 0, stream>>>(x2, yp, outp);
}